// Round 2
// baseline (1098.416 us; speedup 1.0000x reference)
//
#include <hip/hip_runtime.h>
#include <hip/hip_bf16.h>

#define BB 4
#define SS 2048
#define DD 1024
#define HH 16
#define HDD 64
#define MM (BB*SS)   // 8192

typedef __attribute__((ext_vector_type(4))) float f32x4;
typedef __attribute__((ext_vector_type(4))) _Float16 f16x4;
typedef __attribute__((ext_vector_type(8))) _Float16 f16x8;
typedef __attribute__((ext_vector_type(4))) unsigned int u32x4;

// D = A*B + C, fp16 16x16x32 (fp32 accum). Layouts (gfx950, HW-verified family):
//  A[m][k]: m=lane&15, k = 4*(lane>>4) + (e&3) + 16*(e>>2)
//  B[k][n]: n=lane&15, k = same split pattern
//  D[m][n]: n=lane&15, m = 4*(lane>>4) + reg      [m89]
// Note: A/B share the same k-permutation, so any consistent choice gives the
// correct dot product; the split form is what lets the scores D-fragment feed
// the PV B-operand with zero cross-lane traffic.
__device__ inline f32x4 mfma16(f16x8 a, f16x8 b, f32x4 c) {
  return __builtin_amdgcn_mfma_f32_16x16x32_f16(a, b, c, 0, 0, 0);
}

__device__ inline f16x8 comb(f16x4 lo, f16x4 hi) {
  return __builtin_shufflevector(lo, hi, 0, 1, 2, 3, 4, 5, 6, 7);
}

// one fragment: 8B at p (k-half 0..15) and 8B at p+16 elems (k-half 16..31)
__device__ inline f16x8 ld_frag(const _Float16* p) {
  f16x4 lo = *reinterpret_cast<const f16x4*>(p);
  f16x4 hi = *reinterpret_cast<const f16x4*>(p + 16);
  return comb(lo, hi);
}

// ---------------- fp32 -> fp16 conversion of X ----------------
__global__ __launch_bounds__(256) void cvt_x_kernel(
    const float* __restrict__ x, _Float16* __restrict__ xh, int n4) {
  int i = blockIdx.x * 256 + threadIdx.x;
  int stride = gridDim.x * 256;
  for (; i < n4; i += stride) {
    f32x4 v = reinterpret_cast<const f32x4*>(x)[i];
    reinterpret_cast<f16x4*>(xh)[i] = __builtin_convertvector(v, f16x4);
  }
}

// ---------------- transpose + convert weights: Wt[w][n][k] = W[k][n] ----------------
__global__ __launch_bounds__(256) void cvt_w_kernel(
    const float* __restrict__ Wq, const float* __restrict__ Wk,
    const float* __restrict__ Wv, _Float16* __restrict__ Wt) {
  __shared__ float tile[32][33];
  const int w = blockIdx.z;
  const float* W = (w == 0) ? Wq : (w == 1) ? Wk : Wv;
  _Float16* outp = Wt + (size_t)w * DD * DD;
  const int n0 = blockIdx.x * 32, k0 = blockIdx.y * 32;
  const int tx = threadIdx.x, ty = threadIdx.y;  // 32 x 8
#pragma unroll
  for (int i = 0; i < 32; i += 8)
    tile[ty + i][tx] = W[(size_t)(k0 + ty + i) * DD + n0 + tx];
  __syncthreads();
#pragma unroll
  for (int i = 0; i < 32; i += 8)
    outp[(size_t)(n0 + ty + i) * DD + k0 + tx] = (_Float16)tile[tx][ty + i];
}

// ---------------- QKV GEMM: C = Xh(8192x1024) * W (via Wt[n][k]) + bias ----------------
// BM=BN=128, BK=32, 256 threads (4 waves, 2x2), each wave 64x64 (4x4 MFMA tiles)
#define LDT 40  // 32 + 8 pad
__global__ __launch_bounds__(256) void qkv_gemm_kernel(
    const _Float16* __restrict__ Xh, const _Float16* __restrict__ Wt,
    const float* __restrict__ bq, const float* __restrict__ bk, const float* __restrict__ bv,
    _Float16* __restrict__ Qh, _Float16* __restrict__ Kh,
    _Float16* __restrict__ Vt) {
  __shared__ _Float16 At[128 * LDT];
  __shared__ _Float16 Bt[128 * LDT];
  const int w = blockIdx.y;
  const _Float16* Wp = Wt + (size_t)w * DD * DD;
  const int tid = threadIdx.x;
  const int lane = tid & 63, wave = tid >> 6;
  const int g = lane >> 4, r = lane & 15;
  const int mt = blockIdx.x & 63, nt = blockIdx.x >> 6;
  const int m0 = mt * 128, n0 = nt * 128;
  const int wr = wave >> 1, wc = wave & 1;

  f32x4 acc[4][4];
#pragma unroll
  for (int i = 0; i < 4; ++i)
#pragma unroll
    for (int j = 0; j < 4; ++j) { f32x4 z = {0.f, 0.f, 0.f, 0.f}; acc[i][j] = z; }

  const int r0 = tid >> 2, c0 = (tid & 3) * 8;          // chunk 0
  const int r1 = (tid + 256) >> 2, c1 = (tid & 3) * 8;  // chunk 1

  for (int kt = 0; kt < DD; kt += 32) {
    u32x4 a0 = *reinterpret_cast<const u32x4*>(&Xh[(size_t)(m0 + r0) * DD + kt + c0]);
    u32x4 a1 = *reinterpret_cast<const u32x4*>(&Xh[(size_t)(m0 + r1) * DD + kt + c1]);
    u32x4 b0 = *reinterpret_cast<const u32x4*>(&Wp[(size_t)(n0 + r0) * DD + kt + c0]);
    u32x4 b1 = *reinterpret_cast<const u32x4*>(&Wp[(size_t)(n0 + r1) * DD + kt + c1]);
    __syncthreads();
    *reinterpret_cast<u32x4*>(&At[r0 * LDT + c0]) = a0;
    *reinterpret_cast<u32x4*>(&At[r1 * LDT + c1]) = a1;
    *reinterpret_cast<u32x4*>(&Bt[r0 * LDT + c0]) = b0;
    *reinterpret_cast<u32x4*>(&Bt[r1 * LDT + c1]) = b1;
    __syncthreads();

    f16x8 af[4], bf[4];
#pragma unroll
    for (int ms = 0; ms < 4; ++ms)
      af[ms] = ld_frag(&At[(wr * 64 + ms * 16 + r) * LDT + 4 * g]);
#pragma unroll
    for (int ns = 0; ns < 4; ++ns)
      bf[ns] = ld_frag(&Bt[(wc * 64 + ns * 16 + r) * LDT + 4 * g]);
#pragma unroll
    for (int ms = 0; ms < 4; ++ms)
#pragma unroll
      for (int ns = 0; ns < 4; ++ns)
        acc[ms][ns] = mfma16(af[ms], bf[ns], acc[ms][ns]);
  }

  const float* bias = (w == 0) ? bq : (w == 1) ? bk : bv;
#pragma unroll
  for (int ns = 0; ns < 4; ++ns) {
    const int gcol = n0 + wc * 64 + ns * 16 + r;
    const float bv_ = bias[gcol];
    const int h = gcol >> 6, d = gcol & 63;
#pragma unroll
    for (int ms = 0; ms < 4; ++ms) {
#pragma unroll
      for (int reg = 0; reg < 4; ++reg) {
        const int grow = m0 + wr * 64 + ms * 16 + 4 * g + reg;
        const float v = acc[ms][ns][reg] + bv_;
        const int bb = grow >> 11, s = grow & 2047;
        const int bh = bb * HH + h;
        if (w == 0)
          Qh[((size_t)bh * SS + s) * HDD + d] = (_Float16)(v * 0.125f);  // fold hd^-0.5
        else if (w == 1)
          Kh[((size_t)bh * SS + s) * HDD + d] = (_Float16)v;
        else
          Vt[((size_t)bh * HDD + d) * SS + s] = (_Float16)v;
      }
    }
  }
}

// ---------------- flash attention ----------------
// grid (S/64, B*H), 256 thr = 4 waves; wave handles 16 q rows.
// scoresT = mfma(A=K, B=Q) -> D[key][q]: lane owns q = lane&15 for all stats.
// PV: accT = mfma(A=VT, B=PT) -> D[d][q], same lane-q ownership.
__global__ __launch_bounds__(256) void attn_kernel(
    const _Float16* __restrict__ Qh, const _Float16* __restrict__ Kh,
    const _Float16* __restrict__ Vt, const float* __restrict__ mask,
    float* __restrict__ out) {
  __shared__ float maskS[SS];
  const int bh = blockIdx.y;
  const int b = bh >> 4, h = bh & 15;
  const int tid = threadIdx.x, lane = tid & 63, wave = tid >> 6;
  const int g = lane >> 4, r = lane & 15;
  const int q0 = blockIdx.x * 64 + wave * 16;

  for (int i = tid; i < SS; i += 256) maskS[i] = mask[b * SS + i];
  __syncthreads();

  // Q fragments (B-operand), q row = q0 + r, halves d:[0,32) and [32,64)
  const _Float16* Qp = Qh + ((size_t)bh * SS + q0 + r) * HDD;
  f16x8 qf0, qf1;
  {
    f16x4 x0 = *reinterpret_cast<const f16x4*>(Qp + 4 * g);
    f16x4 x1 = *reinterpret_cast<const f16x4*>(Qp + 4 * g + 16);
    f16x4 x2 = *reinterpret_cast<const f16x4*>(Qp + 4 * g + 32);
    f16x4 x3 = *reinterpret_cast<const f16x4*>(Qp + 4 * g + 48);
    qf0 = comb(x0, x1);
    qf1 = comb(x2, x3);
  }

  float m_run = -1e30f, l_run = 0.f;
  f32x4 acc[4];
#pragma unroll
  for (int i = 0; i < 4; ++i) { f32x4 z = {0.f, 0.f, 0.f, 0.f}; acc[i] = z; }

  const _Float16* Kbh = Kh + (size_t)bh * SS * HDD;
  const _Float16* Vbh = Vt + (size_t)bh * HDD * SS;

  for (int kv = 0; kv < SS; kv += 32) {
    // two 16-key score tiles, each accumulated over d=64 (2 MFMAs)
    f32x4 st0, st1;
    {
      const _Float16* Kp = Kbh + (size_t)(kv + r) * HDD + 4 * g;
      f16x8 k0 = comb(*reinterpret_cast<const f16x4*>(Kp),
                      *reinterpret_cast<const f16x4*>(Kp + 16));
      f16x8 k1 = comb(*reinterpret_cast<const f16x4*>(Kp + 32),
                      *reinterpret_cast<const f16x4*>(Kp + 48));
      f32x4 z = {0.f, 0.f, 0.f, 0.f};
      z = mfma16(k0, qf0, z);
      st0 = mfma16(k1, qf1, z);
    }
    {
      const _Float16* Kp = Kbh + (size_t)(kv + 16 + r) * HDD + 4 * g;
      f16x8 k0 = comb(*reinterpret_cast<const f16x4*>(Kp),
                      *reinterpret_cast<const f16x4*>(Kp + 16));
      f16x8 k1 = comb(*reinterpret_cast<const f16x4*>(Kp + 32),
                      *reinterpret_cast<const f16x4*>(Kp + 48));
      f32x4 z = {0.f, 0.f, 0.f, 0.f};
      z = mfma16(k0, qf0, z);
      st1 = mfma16(k1, qf1, z);
    }

    // online softmax; lane owns q=r, holds keys kv + {0,16} + 4g + reg
    float p0[4], p1[4];
    float tm = -1e30f;
#pragma unroll
    for (int j = 0; j < 4; ++j) {
      float s0 = st0[j] + maskS[kv + 4 * g + j];
      float s1 = st1[j] + maskS[kv + 16 + 4 * g + j];
      p0[j] = s0; p1[j] = s1;
      tm = fmaxf(tm, fmaxf(s0, s1));
    }
    tm = fmaxf(tm, __shfl_xor(tm, 16));
    tm = fmaxf(tm, __shfl_xor(tm, 32));
    const float m_new = fmaxf(m_run, tm);
    const float corr = __expf(m_run - m_new);
    float rs = 0.f;
#pragma unroll
    for (int j = 0; j < 4; ++j) {
      p0[j] = __expf(p0[j] - m_new);
      p1[j] = __expf(p1[j] - m_new);
      rs += p0[j] + p1[j];
    }
    rs += __shfl_xor(rs, 16);
    rs += __shfl_xor(rs, 32);
    l_run = l_run * corr + rs;
    m_run = m_new;
#pragma unroll
    for (int i = 0; i < 4; ++i) acc[i] = acc[i] * corr;

    // P^T as B-operand: n=q=r (lane-local), k split: e<4 -> p0[e], e>=4 -> p1[e-4]
    f16x8 pf = { (_Float16)p0[0], (_Float16)p0[1], (_Float16)p0[2], (_Float16)p0[3],
                 (_Float16)p1[0], (_Float16)p1[1], (_Float16)p1[2], (_Float16)p1[3] };

    // PV: A = V^T tiles [16 d][32 keys]
#pragma unroll
    for (int dsb = 0; dsb < 4; ++dsb) {
      const _Float16* Vp = Vbh + (size_t)(dsb * 16 + r) * SS + kv + 4 * g;
      f16x8 vf = comb(*reinterpret_cast<const f16x4*>(Vp),
                      *reinterpret_cast<const f16x4*>(Vp + 16));
      acc[dsb] = mfma16(vf, pf, acc[dsb]);
    }
  }

  const float inv = 1.0f / l_run;
  float* op = out + ((size_t)b * SS + q0 + r) * DD + h * HDD;
#pragma unroll
  for (int dsb = 0; dsb < 4; ++dsb) {
    f32x4 o = { acc[dsb][0] * inv, acc[dsb][1] * inv, acc[dsb][2] * inv, acc[dsb][3] * inv };
    *reinterpret_cast<f32x4*>(op + dsb * 16 + 4 * g) = o;
  }
}

extern "C" void kernel_launch(void* const* d_in, const int* in_sizes, int n_in,
                              void* d_out, int out_size, void* d_ws, size_t ws_size,
                              hipStream_t stream) {
  const float* x    = (const float*)d_in[0];
  const float* mask = (const float*)d_in[1];
  const float* Wq   = (const float*)d_in[2];
  const float* bq   = (const float*)d_in[3];
  const float* Wk   = (const float*)d_in[4];
  const float* bk   = (const float*)d_in[5];
  const float* Wv   = (const float*)d_in[6];
  const float* bv   = (const float*)d_in[7];
  float* out = (float*)d_out;

  _Float16* Xh = (_Float16*)d_ws;                 // 8192*1024 f16
  _Float16* Wt = Xh + (size_t)MM * DD;            // 3*1024*1024
  _Float16* Qh = Wt + (size_t)3 * DD * DD;        // [bh][s][d], pre-scaled
  _Float16* Kh = Qh + (size_t)MM * DD;            // [bh][s][d]
  _Float16* Vt = Kh + (size_t)MM * DD;            // [bh][d][s]

  cvt_x_kernel<<<dim3(2048), dim3(256), 0, stream>>>(x, Xh, MM * DD / 4);
  cvt_w_kernel<<<dim3(32, 32, 3), dim3(32, 8), 0, stream>>>(Wq, Wk, Wv, Wt);
  qkv_gemm_kernel<<<dim3(512, 3), dim3(256), 0, stream>>>(Xh, Wt, bq, bk, bv, Qh, Kh, Vt);
  attn_kernel<<<dim3(SS / 64, BB * HH), dim3(256), 0, stream>>>(Qh, Kh, Vt, mask, out);
}

// Round 3
// 362.039 us; speedup vs baseline: 3.0340x; 3.0340x over previous
//
#include <hip/hip_runtime.h>
#include <hip/hip_bf16.h>

#define BB 4
#define SS 2048
#define DD 1024
#define HH 16
#define HDD 64
#define MM (BB*SS)   // 8192
#define KVB 64
#define NT (SS/KVB)  // 32

typedef __attribute__((ext_vector_type(4))) float f32x4;
typedef __attribute__((ext_vector_type(4))) _Float16 f16x4;
typedef __attribute__((ext_vector_type(8))) _Float16 f16x8;
typedef __attribute__((ext_vector_type(4))) unsigned int u32x4;

// D = A*B + C, fp16 16x16x32 (fp32 accum). Layouts (gfx950, HW-verified family):
//  A[m][k]: m=lane&15, k-map = any bijection shared with B (we use contiguous
//           k=8g+e for QK^T, split k=4g+(e&3)+16(e>>2) for PV)
//  D[m][n]: n=lane&15, m = 4*(lane>>4) + reg      [m89]
__device__ inline f32x4 mfma16(f16x8 a, f16x8 b, f32x4 c) {
  return __builtin_amdgcn_mfma_f32_16x16x32_f16(a, b, c, 0, 0, 0);
}

__device__ inline f16x8 comb(f16x4 lo, f16x4 hi) {
  return __builtin_shufflevector(lo, hi, 0, 1, 2, 3, 4, 5, 6, 7);
}

// split-map fragment: 8B at p (k 0..15) and 8B at p+16 elems (k 16..31)
__device__ inline f16x8 ld_frag(const _Float16* p) {
  f16x4 lo = *reinterpret_cast<const f16x4*>(p);
  f16x4 hi = *reinterpret_cast<const f16x4*>(p + 16);
  return comb(lo, hi);
}

// ---------------- fp32 -> fp16 conversion of X ----------------
__global__ __launch_bounds__(256) void cvt_x_kernel(
    const float* __restrict__ x, _Float16* __restrict__ xh, int n4) {
  int i = blockIdx.x * 256 + threadIdx.x;
  int stride = gridDim.x * 256;
  for (; i < n4; i += stride) {
    f32x4 v = reinterpret_cast<const f32x4*>(x)[i];
    reinterpret_cast<f16x4*>(xh)[i] = __builtin_convertvector(v, f16x4);
  }
}

// ---------------- transpose + convert weights: Wt[w][n][k] = W[k][n] ----------------
__global__ __launch_bounds__(256) void cvt_w_kernel(
    const float* __restrict__ Wq, const float* __restrict__ Wk,
    const float* __restrict__ Wv, _Float16* __restrict__ Wt) {
  __shared__ float tile[32][33];
  const int w = blockIdx.z;
  const float* W = (w == 0) ? Wq : (w == 1) ? Wk : Wv;
  _Float16* outp = Wt + (size_t)w * DD * DD;
  const int n0 = blockIdx.x * 32, k0 = blockIdx.y * 32;
  const int tx = threadIdx.x, ty = threadIdx.y;  // 32 x 8
#pragma unroll
  for (int i = 0; i < 32; i += 8)
    tile[ty + i][tx] = W[(size_t)(k0 + ty + i) * DD + n0 + tx];
  __syncthreads();
#pragma unroll
  for (int i = 0; i < 32; i += 8)
    outp[(size_t)(n0 + ty + i) * DD + k0 + tx] = (_Float16)tile[tx][ty + i];
}

// ---------------- QKV GEMM: C = Xh(8192x1024) * W (via Wt[n][k]) + bias ----------------
#define LDT 40  // 32 + 8 pad
__global__ __launch_bounds__(256) void qkv_gemm_kernel(
    const _Float16* __restrict__ Xh, const _Float16* __restrict__ Wt,
    const float* __restrict__ bq, const float* __restrict__ bk, const float* __restrict__ bv,
    _Float16* __restrict__ Qh, _Float16* __restrict__ Kh,
    _Float16* __restrict__ Vt) {
  __shared__ _Float16 At[128 * LDT];
  __shared__ _Float16 Bt[128 * LDT];
  const int w = blockIdx.y;
  const _Float16* Wp = Wt + (size_t)w * DD * DD;
  const int tid = threadIdx.x;
  const int lane = tid & 63, wave = tid >> 6;
  const int g = lane >> 4, r = lane & 15;
  const int mt = blockIdx.x & 63, nt = blockIdx.x >> 6;
  const int m0 = mt * 128, n0 = nt * 128;
  const int wr = wave >> 1, wc = wave & 1;

  f32x4 acc[4][4];
#pragma unroll
  for (int i = 0; i < 4; ++i)
#pragma unroll
    for (int j = 0; j < 4; ++j) { f32x4 z = {0.f, 0.f, 0.f, 0.f}; acc[i][j] = z; }

  const int r0 = tid >> 2, c0 = (tid & 3) * 8;          // chunk 0
  const int r1 = (tid + 256) >> 2, c1 = (tid & 3) * 8;  // chunk 1

  for (int kt = 0; kt < DD; kt += 32) {
    u32x4 a0 = *reinterpret_cast<const u32x4*>(&Xh[(size_t)(m0 + r0) * DD + kt + c0]);
    u32x4 a1 = *reinterpret_cast<const u32x4*>(&Xh[(size_t)(m0 + r1) * DD + kt + c1]);
    u32x4 b0 = *reinterpret_cast<const u32x4*>(&Wp[(size_t)(n0 + r0) * DD + kt + c0]);
    u32x4 b1 = *reinterpret_cast<const u32x4*>(&Wp[(size_t)(n0 + r1) * DD + kt + c1]);
    __syncthreads();
    *reinterpret_cast<u32x4*>(&At[r0 * LDT + c0]) = a0;
    *reinterpret_cast<u32x4*>(&At[r1 * LDT + c1]) = a1;
    *reinterpret_cast<u32x4*>(&Bt[r0 * LDT + c0]) = b0;
    *reinterpret_cast<u32x4*>(&Bt[r1 * LDT + c1]) = b1;
    __syncthreads();

    f16x8 af[4], bf[4];
#pragma unroll
    for (int ms = 0; ms < 4; ++ms)
      af[ms] = ld_frag(&At[(wr * 64 + ms * 16 + r) * LDT + 4 * g]);
#pragma unroll
    for (int ns = 0; ns < 4; ++ns)
      bf[ns] = ld_frag(&Bt[(wc * 64 + ns * 16 + r) * LDT + 4 * g]);
#pragma unroll
    for (int ms = 0; ms < 4; ++ms)
#pragma unroll
      for (int ns = 0; ns < 4; ++ns)
        acc[ms][ns] = mfma16(af[ms], bf[ns], acc[ms][ns]);
  }

  const float* bias = (w == 0) ? bq : (w == 1) ? bk : bv;
#pragma unroll
  for (int ns = 0; ns < 4; ++ns) {
    const int gcol = n0 + wc * 64 + ns * 16 + r;
    const float bv_ = bias[gcol];
    const int h = gcol >> 6, d = gcol & 63;
#pragma unroll
    for (int ms = 0; ms < 4; ++ms) {
#pragma unroll
      for (int reg = 0; reg < 4; ++reg) {
        const int grow = m0 + wr * 64 + ms * 16 + 4 * g + reg;
        const float v = acc[ms][ns][reg] + bv_;
        const int bb = grow >> 11, s = grow & 2047;
        const int bh = bb * HH + h;
        if (w == 0)
          Qh[((size_t)bh * SS + s) * HDD + d] = (_Float16)(v * 0.125f);  // fold hd^-0.5
        else if (w == 1)
          Kh[((size_t)bh * SS + s) * HDD + d] = (_Float16)v;
        else
          Vt[((size_t)bh * HDD + d) * SS + s] = (_Float16)v;
      }
    }
  }
}

// ---------------- flash attention (LDS-staged, double-buffered) ----------------
// grid (S/128, B*H), 256 thr = 4 waves; wave handles 2 q-subtiles (32 rows).
// Block stages K-tile [64 keys][64 d] and V^T-tile [64 d][64 keys] in LDS,
// XOR-swizzled (elem ^= (row&7)<<3) to kill the 16-way bank conflict of
// 128B-row column reads. scoresT = mfma(A=Ktile, B=Qreg) -> D[key][q]: lane
// owns q=lane&15 for all softmax stats. PV: accT = mfma(A=VT, B=PT) -> D[d][q].
__global__ __launch_bounds__(256) void attn_kernel(
    const _Float16* __restrict__ Qh, const _Float16* __restrict__ Kh,
    const _Float16* __restrict__ Vg, const float* __restrict__ mask,
    float* __restrict__ out) {
  __shared__ _Float16 Ks[2][KVB * 64];
  __shared__ _Float16 Vs[2][KVB * 64];
  __shared__ float maskS[SS];
  const int bh = blockIdx.y;
  const int b = bh >> 4, h = bh & 15;
  const int tid = threadIdx.x, lane = tid & 63, wave = tid >> 6;
  const int g = lane >> 4, r = lane & 15;
  const int q0 = blockIdx.x * 128 + wave * 32;

  for (int i = tid; i < SS; i += 256) maskS[i] = mask[b * SS + i];

  // Q fragments (B-operand, contiguous k-map): q = q0 + qs*16 + r
  f16x8 qf[2][2];
#pragma unroll
  for (int qs = 0; qs < 2; ++qs) {
    const _Float16* Qp = Qh + ((size_t)bh * SS + q0 + qs * 16 + r) * HDD;
    qf[qs][0] = *reinterpret_cast<const f16x8*>(Qp + 8 * g);
    qf[qs][1] = *reinterpret_cast<const f16x8*>(Qp + 32 + 8 * g);
  }

  float m_run[2] = {-1e30f, -1e30f}, l_run[2] = {0.f, 0.f};
  f32x4 acc[2][4];
#pragma unroll
  for (int qs = 0; qs < 2; ++qs)
#pragma unroll
    for (int i = 0; i < 4; ++i) { f32x4 z = {0.f, 0.f, 0.f, 0.f}; acc[qs][i] = z; }

  const _Float16* Kg = Kh + (size_t)bh * SS * HDD;
  const _Float16* Vgb = Vg + (size_t)bh * HDD * SS;

  // staging decomposition: 256 threads cover 64 rows x 64 elems (128B/row);
  // each wave owns 16 rows, lane -> (row = w*16 + i*8 + (lane>>3), col 8*(lane&7))
  const int srow = lane >> 3;         // 0..7
  const int scol = (lane & 7) * 8;    // elem col
  u32x4 kreg[2], vreg[2];

  auto stage_load = [&](int kk) {
#pragma unroll
    for (int i = 0; i < 2; ++i) {
      const int row = wave * 16 + i * 8 + srow;
      kreg[i] = *reinterpret_cast<const u32x4*>(Kg + (size_t)(kk + row) * HDD + scol);
      vreg[i] = *reinterpret_cast<const u32x4*>(Vgb + (size_t)row * SS + kk + scol);
    }
  };
  auto stage_write = [&](int buf) {
#pragma unroll
    for (int i = 0; i < 2; ++i) {
      const int row = wave * 16 + i * 8 + srow;
      const int sw = (row & 7) << 3;
      *reinterpret_cast<u32x4*>(&Ks[buf][row * 64 + (scol ^ sw)]) = kreg[i];
      *reinterpret_cast<u32x4*>(&Vs[buf][row * 64 + (scol ^ sw)]) = vreg[i];
    }
  };

  int cur = 0;
  stage_load(0);
  stage_write(0);
  __syncthreads();

  for (int t = 0; t < NT; ++t) {
    const int kk = t * KVB;
    const bool more = (t + 1) < NT;
    if (more) stage_load(kk + KVB);

#pragma unroll
    for (int sg = 0; sg < 2; ++sg) {
      // scores: two 16-key subtiles, contiguous k-map, K-frag = 1 ds_read_b128
      f32x4 st[2][2];  // [qs][h16]
#pragma unroll
      for (int h16 = 0; h16 < 2; ++h16) {
        const int row = sg * 32 + h16 * 16 + r;
        const int sw = (row & 7) << 3;
        const _Float16* kb = &Ks[cur][row * 64];
        f16x8 a0 = *reinterpret_cast<const f16x8*>(kb + ((8 * g) ^ sw));
        f16x8 a1 = *reinterpret_cast<const f16x8*>(kb + ((32 + 8 * g) ^ sw));
        f32x4 z = {0.f, 0.f, 0.f, 0.f};
        st[0][h16] = mfma16(a1, qf[0][1], mfma16(a0, qf[0][0], z));
        st[1][h16] = mfma16(a1, qf[1][1], mfma16(a0, qf[1][0], z));
      }

      // online softmax (lane owns q = r); keys owned: sg*32 + h16*16 + 4g + j
      f16x8 pf[2];
#pragma unroll
      for (int qs = 0; qs < 2; ++qs) {
        float p0[4], p1[4];
        float tm = -1e30f;
#pragma unroll
        for (int j = 0; j < 4; ++j) {
          float s0 = st[qs][0][j] + maskS[kk + sg * 32 + 4 * g + j];
          float s1 = st[qs][1][j] + maskS[kk + sg * 32 + 16 + 4 * g + j];
          p0[j] = s0; p1[j] = s1;
          tm = fmaxf(tm, fmaxf(s0, s1));
        }
        tm = fmaxf(tm, __shfl_xor(tm, 16));
        tm = fmaxf(tm, __shfl_xor(tm, 32));
        const float m_new = fmaxf(m_run[qs], tm);
        const float corr = __expf(m_run[qs] - m_new);
        float rs = 0.f;
#pragma unroll
        for (int j = 0; j < 4; ++j) {
          p0[j] = __expf(p0[j] - m_new);
          p1[j] = __expf(p1[j] - m_new);
          rs += p0[j] + p1[j];
        }
        rs += __shfl_xor(rs, 16);
        rs += __shfl_xor(rs, 32);
        l_run[qs] = l_run[qs] * corr + rs;
        m_run[qs] = m_new;
#pragma unroll
        for (int i = 0; i < 4; ++i) acc[qs][i] = acc[qs][i] * corr;
        pf[qs] = f16x8{ (_Float16)p0[0], (_Float16)p0[1], (_Float16)p0[2], (_Float16)p0[3],
                        (_Float16)p1[0], (_Float16)p1[1], (_Float16)p1[2], (_Float16)p1[3] };
      }

      // PV: A = V^T [16 d][32 keys] split-map from LDS, B = P^T from regs
#pragma unroll
      for (int dsb = 0; dsb < 4; ++dsb) {
        const int row = dsb * 16 + r;
        const int sw = (row & 7) << 3;
        const _Float16* vb = &Vs[cur][row * 64];
        f16x4 lo = *reinterpret_cast<const f16x4*>(vb + ((sg * 32 + 4 * g) ^ sw));
        f16x4 hi = *reinterpret_cast<const f16x4*>(vb + ((sg * 32 + 16 + 4 * g) ^ sw));
        f16x8 vf = comb(lo, hi);
        acc[0][dsb] = mfma16(vf, pf[0], acc[0][dsb]);
        acc[1][dsb] = mfma16(vf, pf[1], acc[1][dsb]);
      }
    }  // sg

    if (more) stage_write(cur ^ 1);
    __syncthreads();
    cur ^= 1;
  }

#pragma unroll
  for (int qs = 0; qs < 2; ++qs) {
    const float inv = 1.0f / l_run[qs];
    float* op = out + ((size_t)b * SS + q0 + qs * 16 + r) * DD + h * HDD;
#pragma unroll
    for (int dsb = 0; dsb < 4; ++dsb) {
      f32x4 o = { acc[qs][dsb][0] * inv, acc[qs][dsb][1] * inv,
                  acc[qs][dsb][2] * inv, acc[qs][dsb][3] * inv };
      *reinterpret_cast<f32x4*>(op + dsb * 16 + 4 * g) = o;
    }
  }
}

extern "C" void kernel_launch(void* const* d_in, const int* in_sizes, int n_in,
                              void* d_out, int out_size, void* d_ws, size_t ws_size,
                              hipStream_t stream) {
  const float* x    = (const float*)d_in[0];
  const float* mask = (const float*)d_in[1];
  const float* Wq   = (const float*)d_in[2];
  const float* bq   = (const float*)d_in[3];
  const float* Wk   = (const float*)d_in[4];
  const float* bk   = (const float*)d_in[5];
  const float* Wv   = (const float*)d_in[6];
  const float* bv   = (const float*)d_in[7];
  float* out = (float*)d_out;

  _Float16* Xh = (_Float16*)d_ws;                 // 8192*1024 f16
  _Float16* Wt = Xh + (size_t)MM * DD;            // 3*1024*1024
  _Float16* Qh = Wt + (size_t)3 * DD * DD;        // [bh][s][d], pre-scaled
  _Float16* Kh = Qh + (size_t)MM * DD;            // [bh][s][d]
  _Float16* Vt = Kh + (size_t)MM * DD;            // [bh][d][s]

  cvt_x_kernel<<<dim3(2048), dim3(256), 0, stream>>>(x, Xh, MM * DD / 4);
  cvt_w_kernel<<<dim3(32, 32, 3), dim3(32, 8), 0, stream>>>(Wq, Wk, Wv, Wt);
  qkv_gemm_kernel<<<dim3(512, 3), dim3(256), 0, stream>>>(Xh, Wt, bq, bk, bv, Qh, Kh, Vt);
  attn_kernel<<<dim3(SS / 128, BB * HH), dim3(256), 0, stream>>>(Qh, Kh, Vt, mask, out);
}

// Round 5
// 340.941 us; speedup vs baseline: 3.2217x; 1.0619x over previous
//
#include <hip/hip_runtime.h>
#include <hip/hip_bf16.h>

#define BB 4
#define SS 2048
#define DD 1024
#define HH 16
#define HDD 64
#define MM (BB*SS)   // 8192
#define KVB 64
#define NT (SS/KVB)  // 32

typedef __attribute__((ext_vector_type(4))) float f32x4;
typedef __attribute__((ext_vector_type(2))) _Float16 f16x2;
typedef __attribute__((ext_vector_type(4))) _Float16 f16x4;
typedef __attribute__((ext_vector_type(8))) _Float16 f16x8;
typedef __attribute__((ext_vector_type(2))) __fp16 fp16x2_builtin;
typedef __attribute__((ext_vector_type(4))) unsigned int u32x4;

#define LOG2E 1.4426950408889634f
#define QSCALE (0.125f * LOG2E)

__device__ inline float fast_exp2(float x) {
  return __builtin_exp2f(x);
}

// packed f32x2 -> f16x2 (RTZ); bit-cast around the __fp16/_Float16 vector-type mismatch
__device__ inline f16x2 pk2(float a, float b) {
  union { fp16x2_builtin b2; f16x2 h2; } u;
  u.b2 = __builtin_amdgcn_cvt_pkrtz(a, b);
  return u.h2;
}

// D = A*B + C, fp16 16x16x32 (fp32 accum). gfx950 layouts:
//  A/B: k-map = any bijection shared by both operands
//  D[m][n]: n=lane&15, m = 4*(lane>>4) + reg      [m89]
__device__ inline f32x4 mfma16(f16x8 a, f16x8 b, f32x4 c) {
  return __builtin_amdgcn_mfma_f32_16x16x32_f16(a, b, c, 0, 0, 0);
}

__device__ inline f16x8 comb(f16x4 lo, f16x4 hi) {
  return __builtin_shufflevector(lo, hi, 0, 1, 2, 3, 4, 5, 6, 7);
}

// split-map fragment: 8B at p (k 0..15) and 8B at p+16 elems (k 16..31)
__device__ inline f16x8 ld_frag(const _Float16* p) {
  f16x4 lo = *reinterpret_cast<const f16x4*>(p);
  f16x4 hi = *reinterpret_cast<const f16x4*>(p + 16);
  return comb(lo, hi);
}

// ---------------- fp32 -> fp16 conversion of X ----------------
__global__ __launch_bounds__(256) void cvt_x_kernel(
    const float* __restrict__ x, _Float16* __restrict__ xh, int n4) {
  int i = blockIdx.x * 256 + threadIdx.x;
  int stride = gridDim.x * 256;
  for (; i < n4; i += stride) {
    f32x4 v = reinterpret_cast<const f32x4*>(x)[i];
    reinterpret_cast<f16x4*>(xh)[i] = __builtin_convertvector(v, f16x4);
  }
}

// ---------------- mask * log2e ----------------
__global__ __launch_bounds__(256) void mask_scale_kernel(
    const float* __restrict__ m, float* __restrict__ o, int n) {
  int i = blockIdx.x * 256 + threadIdx.x;
  if (i < n) o[i] = m[i] * LOG2E;
}

// ---------------- transpose + convert weights: Wt[w][n][k] = W[k][n] ----------------
__global__ __launch_bounds__(256) void cvt_w_kernel(
    const float* __restrict__ Wq, const float* __restrict__ Wk,
    const float* __restrict__ Wv, _Float16* __restrict__ Wt) {
  __shared__ float tile[32][33];
  const int w = blockIdx.z;
  const float* W = (w == 0) ? Wq : (w == 1) ? Wk : Wv;
  _Float16* outp = Wt + (size_t)w * DD * DD;
  const int n0 = blockIdx.x * 32, k0 = blockIdx.y * 32;
  const int tx = threadIdx.x, ty = threadIdx.y;  // 32 x 8
#pragma unroll
  for (int i = 0; i < 32; i += 8)
    tile[ty + i][tx] = W[(size_t)(k0 + ty + i) * DD + n0 + tx];
  __syncthreads();
#pragma unroll
  for (int i = 0; i < 32; i += 8)
    outp[(size_t)(n0 + ty + i) * DD + k0 + tx] = (_Float16)tile[tx][ty + i];
}

// ---------------- QKV GEMM: C = Xh(8192x1024) * W (via Wt[n][k]) + bias ----------------
#define LDT 40  // 32 + 8 pad
__global__ __launch_bounds__(256) void qkv_gemm_kernel(
    const _Float16* __restrict__ Xh, const _Float16* __restrict__ Wt,
    const float* __restrict__ bq, const float* __restrict__ bk, const float* __restrict__ bv,
    _Float16* __restrict__ Qh, _Float16* __restrict__ Kh,
    _Float16* __restrict__ Vt) {
  __shared__ _Float16 At[128 * LDT];
  __shared__ _Float16 Bt[128 * LDT];
  const int w = blockIdx.y;
  const _Float16* Wp = Wt + (size_t)w * DD * DD;
  const int tid = threadIdx.x;
  const int lane = tid & 63, wave = tid >> 6;
  const int g = lane >> 4, r = lane & 15;
  const int mt = blockIdx.x & 63, nt = blockIdx.x >> 6;
  const int m0 = mt * 128, n0 = nt * 128;
  const int wr = wave >> 1, wc = wave & 1;

  f32x4 acc[4][4];
#pragma unroll
  for (int i = 0; i < 4; ++i)
#pragma unroll
    for (int j = 0; j < 4; ++j) { f32x4 z = {0.f, 0.f, 0.f, 0.f}; acc[i][j] = z; }

  const int r0 = tid >> 2, c0 = (tid & 3) * 8;          // chunk 0
  const int r1 = (tid + 256) >> 2, c1 = (tid & 3) * 8;  // chunk 1

  // prefetched staging registers (T3-minimum: load k+1 before compute of k)
  u32x4 a0 = *reinterpret_cast<const u32x4*>(&Xh[(size_t)(m0 + r0) * DD + c0]);
  u32x4 a1 = *reinterpret_cast<const u32x4*>(&Xh[(size_t)(m0 + r1) * DD + c1]);
  u32x4 b0 = *reinterpret_cast<const u32x4*>(&Wp[(size_t)(n0 + r0) * DD + c0]);
  u32x4 b1 = *reinterpret_cast<const u32x4*>(&Wp[(size_t)(n0 + r1) * DD + c1]);

  for (int kt = 0; kt < DD; kt += 32) {
    __syncthreads();
    *reinterpret_cast<u32x4*>(&At[r0 * LDT + c0]) = a0;
    *reinterpret_cast<u32x4*>(&At[r1 * LDT + c1]) = a1;
    *reinterpret_cast<u32x4*>(&Bt[r0 * LDT + c0]) = b0;
    *reinterpret_cast<u32x4*>(&Bt[r1 * LDT + c1]) = b1;
    __syncthreads();

    const bool more = (kt + 32) < DD;
    if (more) {
      a0 = *reinterpret_cast<const u32x4*>(&Xh[(size_t)(m0 + r0) * DD + kt + 32 + c0]);
      a1 = *reinterpret_cast<const u32x4*>(&Xh[(size_t)(m0 + r1) * DD + kt + 32 + c1]);
      b0 = *reinterpret_cast<const u32x4*>(&Wp[(size_t)(n0 + r0) * DD + kt + 32 + c0]);
      b1 = *reinterpret_cast<const u32x4*>(&Wp[(size_t)(n0 + r1) * DD + kt + 32 + c1]);
    }

    f16x8 af[4], bf[4];
#pragma unroll
    for (int ms = 0; ms < 4; ++ms)
      af[ms] = ld_frag(&At[(wr * 64 + ms * 16 + r) * LDT + 4 * g]);
#pragma unroll
    for (int ns = 0; ns < 4; ++ns)
      bf[ns] = ld_frag(&Bt[(wc * 64 + ns * 16 + r) * LDT + 4 * g]);
#pragma unroll
    for (int ms = 0; ms < 4; ++ms)
#pragma unroll
      for (int ns = 0; ns < 4; ++ns)
        acc[ms][ns] = mfma16(af[ms], bf[ns], acc[ms][ns]);
  }

  const float* bias = (w == 0) ? bq : (w == 1) ? bk : bv;
#pragma unroll
  for (int ns = 0; ns < 4; ++ns) {
    const int gcol = n0 + wc * 64 + ns * 16 + r;
    const float bv_ = bias[gcol];
    const int h = gcol >> 6, d = gcol & 63;
#pragma unroll
    for (int ms = 0; ms < 4; ++ms) {
#pragma unroll
      for (int reg = 0; reg < 4; ++reg) {
        const int grow = m0 + wr * 64 + ms * 16 + 4 * g + reg;
        const float v = acc[ms][ns][reg] + bv_;
        const int bb = grow >> 11, s = grow & 2047;
        const int bh = bb * HH + h;
        if (w == 0)
          Qh[((size_t)bh * SS + s) * HDD + d] = (_Float16)(v * QSCALE);  // fold hd^-0.5 * log2e
        else if (w == 1)
          Kh[((size_t)bh * SS + s) * HDD + d] = (_Float16)v;
        else {
          // permuted V^T: within each 32-key group store key w5 at g-major
          // position so PV A-fragment is one contiguous b128:
          //   w5 < 16:  pos = 8*(w5>>2) + (w5&3)
          //   w5 >= 16: pos = 8*((w5-16)>>2) + 4 + (w5&3)
          const int w5 = s & 31;
          const int pos = (w5 & 16) ? ((((w5 >> 2) & 3) << 3) + 4 + (w5 & 3))
                                    : (((w5 >> 2) << 3) + (w5 & 3));
          const int sp = (s & ~31) | pos;
          Vt[((size_t)bh * HDD + d) * SS + sp] = (_Float16)v;
        }
      }
    }
  }
}

// ---------------- flash attention (LDS-staged, double-buffered, exp2 domain) ----------------
// grid (S/128, B*H), 256 thr = 4 waves; wave handles 2 q-subtiles (32 rows).
// K-tile [64 keys][64 d] and permuted-V^T-tile [64 d][64 keys'] in LDS, XOR-swizzled
// (elem ^= (row&7)<<3). scoresT = mfma(A=K, B=Q) -> D[key][q]: lane owns q=lane&15.
// Defer-max (THR=8, base-2): skip rescale+max-shfl unless a row max grew.
// l kept per-lane partial; reduced once at the end.
__global__ __launch_bounds__(256) void attn_kernel(
    const _Float16* __restrict__ Qh, const _Float16* __restrict__ Kh,
    const _Float16* __restrict__ Vg, const float* __restrict__ maskSc,
    float* __restrict__ out) {
  __shared__ _Float16 Ks[2][KVB * 64];
  __shared__ _Float16 Vs[2][KVB * 64];
  const int bh = blockIdx.y;
  const int b = bh >> 4, h = bh & 15;
  const int tid = threadIdx.x, lane = tid & 63, wave = tid >> 6;
  const int g = lane >> 4, r = lane & 15;
  const int q0 = blockIdx.x * 128 + wave * 32;

  // Q fragments (B-operand, contiguous k-map): q = q0 + qs*16 + r
  f16x8 qf[2][2];
#pragma unroll
  for (int qs = 0; qs < 2; ++qs) {
    const _Float16* Qp = Qh + ((size_t)bh * SS + q0 + qs * 16 + r) * HDD;
    qf[qs][0] = *reinterpret_cast<const f16x8*>(Qp + 8 * g);
    qf[qs][1] = *reinterpret_cast<const f16x8*>(Qp + 32 + 8 * g);
  }

  float m_run[2] = {-1e30f, -1e30f};
  float l_run[2] = {0.f, 0.f};  // per-lane partial
  f32x4 acc[2][4];
#pragma unroll
  for (int qs = 0; qs < 2; ++qs)
#pragma unroll
    for (int i = 0; i < 4; ++i) { f32x4 z = {0.f, 0.f, 0.f, 0.f}; acc[qs][i] = z; }

  const _Float16* Kg = Kh + (size_t)bh * SS * HDD;
  const _Float16* Vgb = Vg + (size_t)bh * HDD * SS;
  const float* mbase = maskSc + b * SS;

  const int srow = lane >> 3;         // 0..7
  const int scol = (lane & 7) * 8;    // elem col
  u32x4 kreg[2], vreg[2];

  auto stage_load = [&](int kk) {
#pragma unroll
    for (int i = 0; i < 2; ++i) {
      const int row = wave * 16 + i * 8 + srow;
      kreg[i] = *reinterpret_cast<const u32x4*>(Kg + (size_t)(kk + row) * HDD + scol);
      vreg[i] = *reinterpret_cast<const u32x4*>(Vgb + (size_t)row * SS + kk + scol);
    }
  };
  auto stage_write = [&](int buf) {
#pragma unroll
    for (int i = 0; i < 2; ++i) {
      const int row = wave * 16 + i * 8 + srow;
      const int sw = (row & 7) << 3;
      *reinterpret_cast<u32x4*>(&Ks[buf][row * 64 + (scol ^ sw)]) = kreg[i];
      *reinterpret_cast<u32x4*>(&Vs[buf][row * 64 + (scol ^ sw)]) = vreg[i];
    }
  };

  int cur = 0;
  stage_load(0);
  stage_write(0);
  __syncthreads();

  for (int t = 0; t < NT; ++t) {
    const int kk = t * KVB;
    const bool more = (t + 1) < NT;
    if (more) stage_load(kk + KVB);

    // mask fragments for this tile (global, L1/L2-hot), issued early
    f32x4 mk[2][2];
#pragma unroll
    for (int sg = 0; sg < 2; ++sg)
#pragma unroll
      for (int h16 = 0; h16 < 2; ++h16)
        mk[sg][h16] = *reinterpret_cast<const f32x4*>(mbase + kk + sg * 32 + h16 * 16 + 4 * g);

#pragma unroll
    for (int sg = 0; sg < 2; ++sg) {
      // scores: two 16-key subtiles, contiguous k-map, K-frag = 1 ds_read_b128
      f32x4 st[2][2];  // [qs][h16]
#pragma unroll
      for (int h16 = 0; h16 < 2; ++h16) {
        const int row = sg * 32 + h16 * 16 + r;
        const int sw = (row & 7) << 3;
        const _Float16* kb = &Ks[cur][row * 64];
        f16x8 a0 = *reinterpret_cast<const f16x8*>(kb + ((8 * g) ^ sw));
        f16x8 a1 = *reinterpret_cast<const f16x8*>(kb + ((32 + 8 * g) ^ sw));
        f32x4 z = {0.f, 0.f, 0.f, 0.f};
        st[0][h16] = mfma16(a1, qf[0][1], mfma16(a0, qf[0][0], z));
        st[1][h16] = mfma16(a1, qf[1][1], mfma16(a0, qf[1][0], z));
      }

      f16x8 pf[2];
#pragma unroll
      for (int qs = 0; qs < 2; ++qs) {
        float p0[4], p1[4];
        float pmax = -1e30f;
#pragma unroll
        for (int j = 0; j < 4; ++j) {
          const float s0 = st[qs][0][j] + mk[sg][0][j];
          const float s1 = st[qs][1][j] + mk[sg][1][j];
          p0[j] = s0; p1[j] = s1;
          pmax = fmaxf(pmax, fmaxf(s0, s1));
        }
        // defer-max: only reduce + rescale when some row's max grew past THR
        if (!__all(pmax <= m_run[qs] + 8.0f)) {
          float tm = fmaxf(pmax, __shfl_xor(pmax, 16));
          tm = fmaxf(tm, __shfl_xor(tm, 32));
          const float m_new = fmaxf(m_run[qs], tm);
          const float corr = fast_exp2(m_run[qs] - m_new);
          l_run[qs] *= corr;
#pragma unroll
          for (int i = 0; i < 4; ++i) acc[qs][i] = acc[qs][i] * corr;
          m_run[qs] = m_new;
        }
        const float mr = m_run[qs];
        float rs = 0.f;
#pragma unroll
        for (int j = 0; j < 4; ++j) {
          p0[j] = fast_exp2(p0[j] - mr);
          p1[j] = fast_exp2(p1[j] - mr);
          rs += p0[j] + p1[j];
        }
        l_run[qs] += rs;
        union { f16x2 h2[4]; f16x8 v; } u;
        u.h2[0] = pk2(p0[0], p0[1]);
        u.h2[1] = pk2(p0[2], p0[3]);
        u.h2[2] = pk2(p1[0], p1[1]);
        u.h2[3] = pk2(p1[2], p1[3]);
        pf[qs] = u.v;
      }

      // PV: A = permuted V^T [16 d][32 keys], one b128 per dsb
#pragma unroll
      for (int dsb = 0; dsb < 4; ++dsb) {
        const int row = dsb * 16 + r;
        const int sw = (row & 7) << 3;
        f16x8 vf = *reinterpret_cast<const f16x8*>(
            &Vs[cur][row * 64 + ((sg * 32 + 8 * g) ^ sw)]);
        acc[0][dsb] = mfma16(vf, pf[0], acc[0][dsb]);
        acc[1][dsb] = mfma16(vf, pf[1], acc[1][dsb]);
      }
    }  // sg

    if (more) stage_write(cur ^ 1);
    __syncthreads();
    cur ^= 1;
  }

#pragma unroll
  for (int qs = 0; qs < 2; ++qs) {
    float l = l_run[qs];
    l += __shfl_xor(l, 16);
    l += __shfl_xor(l, 32);
    const float inv = 1.0f / l;
    float* op = out + ((size_t)b * SS + q0 + qs * 16 + r) * DD + h * HDD;
#pragma unroll
    for (int dsb = 0; dsb < 4; ++dsb) {
      f32x4 o = { acc[qs][dsb][0] * inv, acc[qs][dsb][1] * inv,
                  acc[qs][dsb][2] * inv, acc[qs][dsb][3] * inv };
      *reinterpret_cast<f32x4*>(op + dsb * 16 + 4 * g) = o;
    }
  }
}

extern "C" void kernel_launch(void* const* d_in, const int* in_sizes, int n_in,
                              void* d_out, int out_size, void* d_ws, size_t ws_size,
                              hipStream_t stream) {
  const float* x    = (const float*)d_in[0];
  const float* mask = (const float*)d_in[1];
  const float* Wq   = (const float*)d_in[2];
  const float* bq   = (const float*)d_in[3];
  const float* Wk   = (const float*)d_in[4];
  const float* bk   = (const float*)d_in[5];
  const float* Wv   = (const float*)d_in[6];
  const float* bv   = (const float*)d_in[7];
  float* out = (float*)d_out;

  _Float16* Xh = (_Float16*)d_ws;                 // 8192*1024 f16
  _Float16* Wt = Xh + (size_t)MM * DD;            // 3*1024*1024
  _Float16* Qh = Wt + (size_t)3 * DD * DD;        // [bh][s][d], scaled by 0.125*log2e
  _Float16* Kh = Qh + (size_t)MM * DD;            // [bh][s][d]
  _Float16* Vt = Kh + (size_t)MM * DD;            // [bh][d][s], key-permuted
  float* maskSc = (float*)(Vt + (size_t)MM * DD); // B*S floats, mask*log2e

  cvt_x_kernel<<<dim3(2048), dim3(256), 0, stream>>>(x, Xh, MM * DD / 4);
  mask_scale_kernel<<<dim3((BB * SS + 255) / 256), dim3(256), 0, stream>>>(mask, maskSc, BB * SS);
  cvt_w_kernel<<<dim3(32, 32, 3), dim3(32, 8), 0, stream>>>(Wq, Wk, Wv, Wt);
  qkv_gemm_kernel<<<dim3(512, 3), dim3(256), 0, stream>>>(Xh, Wt, bq, bk, bv, Qh, Kh, Vt);
  attn_kernel<<<dim3(SS / 128, BB * HH), dim3(256), 0, stream>>>(Qh, Kh, Vt, maskSc, out);
}

// Round 6
// 324.034 us; speedup vs baseline: 3.3898x; 1.0522x over previous
//
#include <hip/hip_runtime.h>
#include <hip/hip_bf16.h>

#define BB 4
#define SS 2048
#define DD 1024
#define HH 16
#define HDD 64
#define MM (BB*SS)   // 8192
#define KVB 64
#define NT (SS/KVB)  // 32

typedef __attribute__((ext_vector_type(4))) float f32x4;
typedef __attribute__((ext_vector_type(2))) _Float16 f16x2;
typedef __attribute__((ext_vector_type(4))) _Float16 f16x4;
typedef __attribute__((ext_vector_type(8))) _Float16 f16x8;
typedef __attribute__((ext_vector_type(2))) __fp16 fp16x2_builtin;

#define LOG2E 1.4426950408889634f
#define QSCALE (0.125f * LOG2E)

__device__ inline float fast_exp2(float x) { return __builtin_exp2f(x); }

// packed f32x2 -> f16x2 (RTZ)
__device__ inline f16x2 pk2(float a, float b) {
  union { fp16x2_builtin b2; f16x2 h2; } u;
  u.b2 = __builtin_amdgcn_cvt_pkrtz(a, b);
  return u.h2;
}

// async global->LDS, 16B per lane; LDS dest = wave-uniform base + lane*16 [m97/m104]
__device__ inline void glds16(const void* g, void* l) {
  __builtin_amdgcn_global_load_lds(
      (__attribute__((address_space(1))) void*)(g),
      (__attribute__((address_space(3))) void*)(l), 16, 0, 0);
}

// D = A*B + C, fp16 16x16x32 (fp32 accum). gfx950:
//  A/B k-map: any bijection shared by both operands (we use contiguous k=8g+e
//  where possible; split map where the scores D-layout forces it).
//  D[m][n]: n=lane&15, m = 4*(lane>>4) + reg   [m89]
__device__ inline f32x4 mfma16(f16x8 a, f16x8 b, f32x4 c) {
  return __builtin_amdgcn_mfma_f32_16x16x32_f16(a, b, c, 0, 0, 0);
}

// ---------------- fp32 -> fp16 conversion of X ----------------
__global__ __launch_bounds__(256) void cvt_x_kernel(
    const float* __restrict__ x, _Float16* __restrict__ xh, int n4) {
  int i = blockIdx.x * 256 + threadIdx.x;
  int stride = gridDim.x * 256;
  for (; i < n4; i += stride) {
    f32x4 v = reinterpret_cast<const f32x4*>(x)[i];
    reinterpret_cast<f16x4*>(xh)[i] = __builtin_convertvector(v, f16x4);
  }
}

// ---------------- mask * log2e ----------------
__global__ __launch_bounds__(256) void mask_scale_kernel(
    const float* __restrict__ m, float* __restrict__ o, int n) {
  int i = blockIdx.x * 256 + threadIdx.x;
  if (i < n) o[i] = m[i] * LOG2E;
}

// ---------------- transpose + convert weights: Wt[w][n][k] = W[k][n] ----------------
__global__ __launch_bounds__(256) void cvt_w_kernel(
    const float* __restrict__ Wq, const float* __restrict__ Wk,
    const float* __restrict__ Wv, _Float16* __restrict__ Wt) {
  __shared__ float tile[32][33];
  const int w = blockIdx.z;
  const float* W = (w == 0) ? Wq : (w == 1) ? Wk : Wv;
  _Float16* outp = Wt + (size_t)w * DD * DD;
  const int n0 = blockIdx.x * 32, k0 = blockIdx.y * 32;
  const int tx = threadIdx.x, ty = threadIdx.y;  // 32 x 8
#pragma unroll
  for (int i = 0; i < 32; i += 8)
    tile[ty + i][tx] = W[(size_t)(k0 + ty + i) * DD + n0 + tx];
  __syncthreads();
#pragma unroll
  for (int i = 0; i < 32; i += 8)
    outp[(size_t)(n0 + ty + i) * DD + k0 + tx] = (_Float16)tile[tx][ty + i];
}

// ---------------- QKV GEMM (m97-structure): glds staging + dbuf LDS ----------------
// BM=BN=128, BK=32, 256 thr / 4 waves (2x2), wave tile 64x64 (4x4 frags).
// LDS linear [128][32], both-sides XOR swizzle: source col ^= 8*(row&3),
// read col = 8g ^ 8*(r&3). Fragment = one contiguous b128 (k=8g..8g+7 map).
__global__ __launch_bounds__(256) void qkv_gemm_kernel(
    const _Float16* __restrict__ Xh, const _Float16* __restrict__ Wt,
    const float* __restrict__ bq, const float* __restrict__ bk, const float* __restrict__ bv,
    _Float16* __restrict__ Qh, _Float16* __restrict__ Kh,
    _Float16* __restrict__ Vt) {
  __shared__ _Float16 At[2][128 * 32];
  __shared__ _Float16 Bt[2][128 * 32];
  const int w = blockIdx.y;
  const _Float16* Wp = Wt + (size_t)w * DD * DD;
  const int tid = threadIdx.x;
  const int lane = tid & 63, wave = tid >> 6;
  const int g = lane >> 4, r = lane & 15;
  const int mt = blockIdx.x & 63, nt = blockIdx.x >> 6;
  const int m0 = mt * 128, n0 = nt * 128;
  const int wr = wave >> 1, wc = wave & 1;

  f32x4 acc[4][4];
#pragma unroll
  for (int i = 0; i < 4; ++i)
#pragma unroll
    for (int j = 0; j < 4; ++j) { f32x4 z = {0.f, 0.f, 0.f, 0.f}; acc[i][j] = z; }

  // staging geometry: chunk c = 16 rows; lane -> row 16c + (l>>2), src col pre-swizzled
  const int srow = lane >> 2;                       // 0..15
  const int scol = 8 * ((lane & 3) ^ (srow & 3));   // inverse-swizzled source col
  const int cA = (8 * g) ^ (8 * (r & 3));           // swizzled read col

  auto stage = [&](int kt, int buf) {
#pragma unroll
    for (int i = 0; i < 2; ++i) {
      const int c = wave * 2 + i;
      glds16(Xh + (size_t)(m0 + 16 * c + srow) * DD + kt + scol, &At[buf][c * 512]);
      glds16(Wp + (size_t)(n0 + 16 * c + srow) * DD + kt + scol, &Bt[buf][c * 512]);
    }
  };

  stage(0, 0);
  __syncthreads();
  int buf = 0;
  for (int kt = 0; kt < DD; kt += 32) {
    if (kt + 32 < DD) stage(kt + 32, buf ^ 1);

    f16x8 af[4], bf[4];
#pragma unroll
    for (int ms = 0; ms < 4; ++ms)
      af[ms] = *reinterpret_cast<const f16x8*>(&At[buf][(wr * 64 + ms * 16 + r) * 32 + cA]);
#pragma unroll
    for (int ns = 0; ns < 4; ++ns)
      bf[ns] = *reinterpret_cast<const f16x8*>(&Bt[buf][(wc * 64 + ns * 16 + r) * 32 + cA]);
#pragma unroll
    for (int ms = 0; ms < 4; ++ms)
#pragma unroll
      for (int ns = 0; ns < 4; ++ns)
        acc[ms][ns] = mfma16(af[ms], bf[ns], acc[ms][ns]);

    __syncthreads();
    buf ^= 1;
  }

  const float* bias = (w == 0) ? bq : (w == 1) ? bk : bv;
#pragma unroll
  for (int ns = 0; ns < 4; ++ns) {
    const int gcol = n0 + wc * 64 + ns * 16 + r;
    const float bv_ = bias[gcol];
    const int h = gcol >> 6, d = gcol & 63;
#pragma unroll
    for (int ms = 0; ms < 4; ++ms) {
#pragma unroll
      for (int reg = 0; reg < 4; ++reg) {
        const int grow = m0 + wr * 64 + ms * 16 + 4 * g + reg;
        const float v = acc[ms][ns][reg] + bv_;
        const int bb = grow >> 11, s = grow & 2047;
        const int bh = bb * HH + h;
        if (w == 0)
          Qh[((size_t)bh * SS + s) * HDD + d] = (_Float16)(v * QSCALE);  // hd^-0.5 * log2e
        else if (w == 1)
          Kh[((size_t)bh * SS + s) * HDD + d] = (_Float16)v;
        else {
          // permuted V^T: key w5 stored at g-major pos so PV A-frag is one b128
          const int w5 = s & 31;
          const int pos = (w5 & 16) ? ((((w5 >> 2) & 3) << 3) + 4 + (w5 & 3))
                                    : (((w5 >> 2) << 3) + (w5 & 3));
          const int sp = (s & ~31) | pos;
          Vt[((size_t)bh * HDD + d) * SS + sp] = (_Float16)v;
        }
      }
    }
  }
}

// ---------------- flash attention (glds-staged, dbuf, 8 waves) ----------------
// grid (S/128, B*H), 512 thr = 8 waves; wave handles 16 q rows.
// K tile [64 keys][64 d], permuted-V^T tile [64 d][64 keys'] in LDS; both-sides
// XOR swizzle col ^= 8*(row&7) via pre-swizzled glds SOURCE (rows are 128B so
// the XOR stays in-row; row&7 == r&7 for all reads -> lane-constant offsets).
// scoresT = mfma(A=K, B=Q) -> D[key][q], lane owns q=lane&15; defer-max (THR=8).
__global__ __launch_bounds__(512) void attn_kernel(
    const _Float16* __restrict__ Qh, const _Float16* __restrict__ Kh,
    const _Float16* __restrict__ Vg, const float* __restrict__ maskSc,
    float* __restrict__ out) {
  __shared__ _Float16 Ks[2][KVB * 64];
  __shared__ _Float16 Vs[2][KVB * 64];
  const int bh = blockIdx.y;
  const int b = bh >> 4, h = bh & 15;
  const int tid = threadIdx.x, lane = tid & 63, w = tid >> 6;  // 8 waves
  const int g = lane >> 4, r = lane & 15;
  const int q0 = blockIdx.x * 128 + w * 16;

  const _Float16* Kg = Kh + (size_t)bh * SS * HDD;
  const _Float16* Vgb = Vg + (size_t)bh * HDD * SS;
  const float* mbase = maskSc + b * SS;

  // Q fragments (B-operand, contiguous k-map): q row = q0 + r
  const _Float16* Qp = Qh + ((size_t)bh * SS + q0 + r) * HDD;
  const f16x8 qf0 = *reinterpret_cast<const f16x8*>(Qp + 8 * g);
  const f16x8 qf1 = *reinterpret_cast<const f16x8*>(Qp + 32 + 8 * g);

  float m_run = -1e30f, l_run = 0.f;
  f32x4 acc[4];
#pragma unroll
  for (int i = 0; i < 4; ++i) { f32x4 z = {0.f, 0.f, 0.f, 0.f}; acc[i] = z; }

  // staging: wave w stages K rows 8w..8w+7 and V rows 8w..8w+7 (1 glds each)
  const int sr = lane >> 3;                   // 0..7
  const int sc = 8 * ((lane & 7) ^ sr);       // inverse-swizzled source col
  const _Float16* kSrc = Kg + (size_t)(w * 8 + sr) * HDD + sc;
  const _Float16* vSrc = Vgb + (size_t)(w * 8 + sr) * SS + sc;
  const int wdst = w * 512;

  const int c0 = (8 * g) ^ (8 * (r & 7));     // swizzled read col (lane-constant)

  auto prefetch = [&](int t, int buf) {
    const int kk = t * KVB;
    glds16(kSrc + (size_t)kk * HDD, &Ks[buf][wdst]);
    glds16(vSrc + kk, &Vs[buf][wdst]);
  };

  prefetch(0, 0);
  __syncthreads();

  for (int t = 0; t < NT; ++t) {
    if (t + 1 < NT) prefetch(t + 1, (t + 1) & 1);
    const _Float16* kb = &Ks[t & 1][0];
    const _Float16* vb = &Vs[t & 1][0];
    const int kk = t * KVB;

    f32x4 mk[2][2];
#pragma unroll
    for (int sg = 0; sg < 2; ++sg)
#pragma unroll
      for (int h16 = 0; h16 < 2; ++h16)
        mk[sg][h16] = *reinterpret_cast<const f32x4*>(mbase + kk + sg * 32 + h16 * 16 + 4 * g);

#pragma unroll
    for (int sg = 0; sg < 2; ++sg) {
      f32x4 st[2];
#pragma unroll
      for (int h16 = 0; h16 < 2; ++h16) {
        const int row = sg * 32 + h16 * 16 + r;
        f16x8 a0 = *reinterpret_cast<const f16x8*>(kb + row * 64 + c0);
        f16x8 a1 = *reinterpret_cast<const f16x8*>(kb + row * 64 + (c0 ^ 32));
        f32x4 z = {0.f, 0.f, 0.f, 0.f};
        st[h16] = mfma16(a1, qf1, mfma16(a0, qf0, z));
      }

      float p0[4], p1[4];
      float pmax = -1e30f;
#pragma unroll
      for (int j = 0; j < 4; ++j) {
        const float s0 = st[0][j] + mk[sg][0][j];
        const float s1 = st[1][j] + mk[sg][1][j];
        p0[j] = s0; p1[j] = s1;
        pmax = fmaxf(pmax, fmaxf(s0, s1));
      }
      // defer-max: reduce + rescale only when a row max grows past THR
      if (!__all(pmax <= m_run + 8.0f)) {
        float tm = fmaxf(pmax, __shfl_xor(pmax, 16));
        tm = fmaxf(tm, __shfl_xor(tm, 32));
        const float m_new = fmaxf(m_run, tm);
        const float corr = fast_exp2(m_run - m_new);
        l_run *= corr;
#pragma unroll
        for (int i = 0; i < 4; ++i) acc[i] = acc[i] * corr;
        m_run = m_new;
      }
      const float mr = m_run;
      float rs = 0.f;
#pragma unroll
      for (int j = 0; j < 4; ++j) {
        p0[j] = fast_exp2(p0[j] - mr);
        p1[j] = fast_exp2(p1[j] - mr);
        rs += p0[j] + p1[j];
      }
      l_run += rs;
      union { f16x2 h2[4]; f16x8 v; } u;
      u.h2[0] = pk2(p0[0], p0[1]);
      u.h2[1] = pk2(p0[2], p0[3]);
      u.h2[2] = pk2(p1[0], p1[1]);
      u.h2[3] = pk2(p1[2], p1[3]);
      const f16x8 pf = u.v;

      // PV: A = permuted V^T [16 d][32 keys], one b128 per dsb
#pragma unroll
      for (int dsb = 0; dsb < 4; ++dsb) {
        const int vrow = dsb * 16 + r;
        f16x8 vf = *reinterpret_cast<const f16x8*>(vb + vrow * 64 + (c0 ^ (sg * 32)));
        acc[dsb] = mfma16(vf, pf, acc[dsb]);
      }
    }  // sg

    __syncthreads();
  }

  float l = l_run;
  l += __shfl_xor(l, 16);
  l += __shfl_xor(l, 32);
  const float inv = 1.0f / l;
  float* op = out + ((size_t)b * SS + q0 + r) * DD + h * HDD;
#pragma unroll
  for (int dsb = 0; dsb < 4; ++dsb) {
    f32x4 o = { acc[dsb][0] * inv, acc[dsb][1] * inv,
                acc[dsb][2] * inv, acc[dsb][3] * inv };
    *reinterpret_cast<f32x4*>(op + dsb * 16 + 4 * g) = o;
  }
}

extern "C" void kernel_launch(void* const* d_in, const int* in_sizes, int n_in,
                              void* d_out, int out_size, void* d_ws, size_t ws_size,
                              hipStream_t stream) {
  const float* x    = (const float*)d_in[0];
  const float* mask = (const float*)d_in[1];
  const float* Wq   = (const float*)d_in[2];
  const float* bq   = (const float*)d_in[3];
  const float* Wk   = (const float*)d_in[4];
  const float* bk   = (const float*)d_in[5];
  const float* Wv   = (const float*)d_in[6];
  const float* bv   = (const float*)d_in[7];
  float* out = (float*)d_out;

  _Float16* Xh = (_Float16*)d_ws;                 // 8192*1024 f16
  _Float16* Wt = Xh + (size_t)MM * DD;            // 3*1024*1024
  _Float16* Qh = Wt + (size_t)3 * DD * DD;        // [bh][s][d], scaled 0.125*log2e
  _Float16* Kh = Qh + (size_t)MM * DD;            // [bh][s][d]
  _Float16* Vt = Kh + (size_t)MM * DD;            // [bh][d][s], key-permuted
  float* maskSc = (float*)(Vt + (size_t)MM * DD); // B*S floats, mask*log2e

  cvt_x_kernel<<<dim3(2048), dim3(256), 0, stream>>>(x, Xh, MM * DD / 4);
  mask_scale_kernel<<<dim3((BB * SS + 255) / 256), dim3(256), 0, stream>>>(mask, maskSc, BB * SS);
  cvt_w_kernel<<<dim3(32, 32, 3), dim3(32, 8), 0, stream>>>(Wq, Wk, Wv, Wt);
  qkv_gemm_kernel<<<dim3(512, 3), dim3(256), 0, stream>>>(Xh, Wt, bq, bk, bv, Qh, Kh, Vt);
  attn_kernel<<<dim3(SS / 128, BB * HH), dim3(512), 0, stream>>>(Qh, Kh, Vt, maskSc, out);
}